// Round 9
// baseline (252.133 us; speedup 1.0000x reference)
//
#include <hip/hip_runtime.h>
#include <math.h>

// Problem constants (fixed by setup_inputs in the reference)
constexpr int B_ = 2, C_ = 64, H_ = 180, W_ = 360;
constexpr int HW = H_ * W_;             // 64800
constexpr int Hp = H_ + 2, Wp = W_ + 2; // padded dims 182 x 362
constexpr int O_ = 2 * C_;              // 128 velocity outputs

// NOTE (round-5 lesson): the reference's seam mapping is DISCONTINUOUS in lon
// (remainder wraps + clamped 1-px-pad bicubic). Coordinate math must stay
// bit-close to fp32 libm: asinf/atan2f/exact-division remainder only.
__device__ __forceinline__ float frem(float x, float y) {
    return x - floorf(x / y) * y;            // IEEE division, matches jnp
}
// remainder(x, 2): x*0.5f is EXACT (pow2), floor identical to floor(x/2).
__device__ __forceinline__ float frem2(float x) {
    return x - floorf(x * 0.5f) * 2.0f;
}

// bicubic weights, A = -0.75
__device__ __forceinline__ float cub1(float x) {   // |t| <= 1
    return (1.25f * x - 2.25f) * x * x + 1.0f;
}
__device__ __forceinline__ float cub2(float x) {   // 1 < |t| < 2
    return ((-0.75f * x + 3.75f) * x - 6.0f) * x + 3.0f;
}

// Read geo_cyclic_pad(hidden,1)[y][x] directly from the unpadded image.
__device__ __forceinline__ float fetch_pad(const float* __restrict__ img, int y, int x) {
    int wc = x - 1;
    if (x == 0)      wc = W_ - 1;
    if (x == Wp - 1) wc = 0;
    int hh = y - 1;
    bool top = (y == 0), bot = (y == Hp - 1);
    if (top) hh = 0;
    if (bot) hh = H_ - 1;
    if (top || bot) { wc += W_ / 2; if (wc >= W_) wc -= W_; }
    return img[hh * W_ + wc];
}

// Shared phase-2 math: departure point + bicubic sample for one (b,c,px).
__device__ __forceinline__ float advect_one(
    const float* __restrict__ img,   // channel slice (H,W)
    float u, float v, float dt,
    float sp, float cp, float lon_p,
    float min_lat, float min_lon, float inv_dlat, float inv_dlon)
{
    const float two_pi = 6.28318530717958647f;
    const float sxw = (float)W_ / (float)Wp;
    const float syh = (float)H_ / (float)Hp;

    const float lon_pr = -u * dt;
    const float lat_pr = -v * dt;
    float slp, clp, slo, clo;
    __sincosf(lat_pr, &slp, &clp);
    __sincosf(lon_pr, &slo, &clo);
    float sin_lat = slp * cp + clp * clo * sp;
    sin_lat = fminf(fmaxf(sin_lat, -1.0f + 1e-7f), 1.0f - 1e-7f);
    const float lat = asinf(sin_lat);
    const float num = clp * slo;
    const float den = clp * clo * cp - slp * sp;
    const float lon = frem(lon_p + atan2f(num, den) + two_pi, two_pi);

    float gx = (lon - min_lon) * inv_dlon - 1.0f;
    float gy = (lat - min_lat) * inv_dlat - 1.0f;
    gx = frem2(gx + 1.0f) - 1.0f;
    const bool left  = (gx <= 0.0f);
    const bool outer = (fabsf(gy) > 1.0f);
    if (outer) gx += left ? 1.0f : -1.0f;
    if (gy < -1.0f)     gy = -(2.0f + gy);
    else if (gy > 1.0f) gy = 2.0f - gy;
    gx *= sxw;
    gy *= syh;

    const float ix = (gx + 1.0f) * 0.5f * (float)(Wp - 1);
    const float iy = (gy + 1.0f) * 0.5f * (float)(Hp - 1);
    const float fx0 = floorf(ix), fy0 = floorf(iy);
    const float tx = ix - fx0, ty = iy - fy0;
    const int jx = (int)fx0, jy = (int)fy0;

    float t[16];
    const bool interior = (jx >= 2) & (jx <= Wp - 4) & (jy >= 2) & (jy <= Hp - 4);
    if (__all(interior)) {
        const float* __restrict__ p = img + (jy - 2) * W_ + (jx - 2);
#pragma unroll
        for (int r = 0; r < 4; ++r)
#pragma unroll
            for (int cc = 0; cc < 4; ++cc)
                t[r * 4 + cc] = p[r * W_ + cc];
    } else {
        int xs[4], ys[4];
#pragma unroll
        for (int r = 0; r < 4; ++r) {
            xs[r] = min(max(jx - 1 + r, 0), Wp - 1);
            ys[r] = min(max(jy - 1 + r, 0), Hp - 1);
        }
#pragma unroll
        for (int r = 0; r < 4; ++r)
#pragma unroll
            for (int cc = 0; cc < 4; ++cc)
                t[r * 4 + cc] = fetch_pad(img, ys[r], xs[cc]);
    }

    const float wx0 = cub2(tx + 1.0f), wx1 = cub1(tx);
    const float wx2 = cub1(1.0f - tx), wx3 = cub2(2.0f - tx);
    const float wy0 = cub2(ty + 1.0f), wy1 = cub1(ty);
    const float wy2 = cub1(1.0f - ty), wy3 = cub2(2.0f - ty);

    const float r0 = fmaf(wx3, t[3],  fmaf(wx2, t[2],  fmaf(wx1, t[1],  wx0 * t[0])));
    const float r1 = fmaf(wx3, t[7],  fmaf(wx2, t[6],  fmaf(wx1, t[5],  wx0 * t[4])));
    const float r2 = fmaf(wx3, t[11], fmaf(wx2, t[10], fmaf(wx1, t[9],  wx0 * t[8])));
    const float r3 = fmaf(wx3, t[15], fmaf(wx2, t[14], fmaf(wx1, t[13], wx0 * t[12])));

    return fmaf(wy3, r3, fmaf(wy2, r2, fmaf(wy1, r1, wy0 * r0)));
}

// ---------------- Phase 1: uv = hidden x W_vel^T + b  (B,128,HW) ----------------
// I$-resident body: k-loop FORCED rolled (#pragma unroll 1) -> ~4.7 KB body
// (round-8 lesson: full unroll made a ~45 KB body that thrashed the 32 KB I$,
//  pinning this kernel at ~120 us regardless of data-side tuning).
// Prefetch depth 8 = 1024 FMA-issue cycles, covers ~900-cyc HBM latency.
constexpr int P1_PXT = 256;
constexpr int P1_OG  = 2;
constexpr int P1_OPG = O_ / P1_OG;      // 64 outputs per group
constexpr int P1_TILES = (HW + P1_PXT - 1) / P1_PXT; // 254

__global__ __launch_bounds__(P1_PXT, 4) void nsl_vel(
    const float* __restrict__ hidden, const float* __restrict__ W_vel,
    const float* __restrict__ b_vel, float* __restrict__ uv)
{
    const int bid  = blockIdx.x;
    const int tile = bid % P1_TILES;
    const int og   = (bid / P1_TILES) % P1_OG;
    const int b    = bid / (P1_TILES * P1_OG);
    const int px   = tile * P1_PXT + threadIdx.x;
    if (px >= HW) return;

    float acc[P1_OPG];
#pragma unroll
    for (int j = 0; j < P1_OPG; ++j) acc[j] = b_vel[og * P1_OPG + j];

    const float* hb = hidden + (size_t)b * C_ * HW + px;
    const float* Wg = W_vel + (size_t)og * P1_OPG * C_;

    float xf[8];
#pragma unroll
    for (int t = 0; t < 8; ++t) xf[t] = hb[(size_t)t * HW];

#pragma unroll 1
    for (int k0 = 0; k0 < C_; k0 += 8) {
        float xc[8];
#pragma unroll
        for (int t = 0; t < 8; ++t) xc[t] = xf[t];     // reg-rename, ~free
        if (k0 + 8 < C_) {
#pragma unroll
            for (int t = 0; t < 8; ++t) xf[t] = hb[(size_t)(k0 + 8 + t) * HW];
        }
        // k-chain per output stays ascending -> bitwise-identical uv.
        // Per j: 8 contiguous W floats (s_load_dwordx8-friendly).
#pragma unroll
        for (int j = 0; j < P1_OPG; ++j) {
            const float* wr = Wg + (size_t)j * C_ + k0;
#pragma unroll
            for (int t = 0; t < 8; ++t)
                acc[j] = fmaf(wr[t], xc[t], acc[j]);
        }
    }

    float* o = uv + ((size_t)b * O_ + og * P1_OPG) * HW + px;
#pragma unroll
    for (int j = 0; j < P1_OPG; ++j) o[(size_t)j * HW] = acc[j];
}

// ---------------- Phase 2: one thread per (b,c,px) ----------------
// lat_grid[b,h,w] == lat[h] exactly (reference broadcasts a 1-D linspace),
// so sincos(lat) is computed once per block for 180 rows (bit-identical
// __sincosf on bit-identical inputs) and fetched via broadcast LDS reads.
// Grid divides exactly: B*C*HW = 8,294,400 = 32400 * 256 -> no early returns
// before __syncthreads.
__global__ __launch_bounds__(256, 6) void nsl_advect(
    const float* __restrict__ hidden,    // (B,C,H,W)
    const float* __restrict__ lat_grid,  // (B,H,W)
    const float* __restrict__ lon_grid,  // (B,H,W)
    const float* __restrict__ uv,        // (B,128,HW) from phase 1
    const float* __restrict__ dt_p,
    float* __restrict__ out)             // (B,C,H,W)
{
    __shared__ float s_sp[H_], s_cp[H_];
    const int tid = threadIdx.x;
    if (tid < H_) {
        float s, c;
        __sincosf(lat_grid[(size_t)tid * W_], &s, &c);
        s_sp[tid] = s;
        s_cp[tid] = c;
    }
    __syncthreads();

    const int idx = blockIdx.x * 256 + tid;
    const int px = idx % HW;
    const int bc = idx / HW;            // b*C + c
    const int b  = bc / C_;
    const int c  = bc - b * C_;

    const float dt      = dt_p[0];
    const float min_lat = lat_grid[0];
    const float max_lat = lat_grid[(H_ - 1) * W_];
    const float min_lon = lon_grid[0];
    const float max_lon = lon_grid[W_ - 1];
    const float inv_dlat = 2.0f / (max_lat - min_lat);
    const float inv_dlon = 2.0f / (max_lon - min_lon);

    const int h = px / W_;              // compiler magic-div
    const float sp = s_sp[h];
    const float cp = s_cp[h];
    const float lon_p = lon_grid[(size_t)b * HW + px];

    const float u = uv[((size_t)b * O_ + c) * HW + px];
    const float v = uv[((size_t)b * O_ + C_ + c) * HW + px];

    const float* __restrict__ img = hidden + (size_t)bc * HW;
    out[(size_t)bc * HW + px] = advect_one(img, u, v, dt, sp, cp, lon_p,
                                           min_lat, min_lon, inv_dlat, inv_dlon);
}

// ---------------- Fallback: fused kernel (round-6 structure, passing) ----------------
constexpr int FB_CG = 4, FB_CPT = C_ / FB_CG, FB_PXT = 256;
constexpr int FB_TILES = (HW + FB_PXT - 1) / FB_PXT;

__global__ __launch_bounds__(FB_PXT, 6) void nsl_fused(
    const float* __restrict__ hidden, const float* __restrict__ lat_grid,
    const float* __restrict__ lon_grid, const float* __restrict__ W_vel,
    const float* __restrict__ b_vel, const float* __restrict__ dt_p,
    float* __restrict__ out)
{
    const int bid  = blockIdx.x;
    const int tile = bid % FB_TILES;
    const int cg   = (bid / FB_TILES) % FB_CG;
    const int b    = bid / (FB_TILES * FB_CG);
    const int px   = tile * FB_PXT + threadIdx.x;
    if (px >= HW) return;

    const float dt      = dt_p[0];
    const float min_lat = lat_grid[0];
    const float max_lat = lat_grid[(H_ - 1) * W_];
    const float min_lon = lon_grid[0];
    const float max_lon = lon_grid[W_ - 1];
    const float inv_dlat = 2.0f / (max_lat - min_lat);
    const float inv_dlon = 2.0f / (max_lon - min_lon);

    const float lat_p = lat_grid[(size_t)b * HW + px];
    const float lon_p = lon_grid[(size_t)b * HW + px];
    float sp, cp;
    __sincosf(lat_p, &sp, &cp);

    float u[FB_CPT], v[FB_CPT];
#pragma unroll
    for (int i = 0; i < FB_CPT; ++i) {
        u[i] = b_vel[cg * FB_CPT + i];
        v[i] = b_vel[C_ + cg * FB_CPT + i];
    }
    const float* hb = hidden + (size_t)b * C_ * HW + px;
#pragma unroll 2
    for (int k = 0; k < C_; ++k) {
        const float x = hb[(size_t)k * HW];
#pragma unroll
        for (int i = 0; i < FB_CPT; ++i) {
            u[i] = fmaf(W_vel[(size_t)(cg * FB_CPT + i) * C_ + k], x, u[i]);
            v[i] = fmaf(W_vel[(size_t)(C_ + cg * FB_CPT + i) * C_ + k], x, v[i]);
        }
    }

    for (int i = 0; i < FB_CPT; ++i) {
        const int c = cg * FB_CPT + i;
        const float* __restrict__ img = hidden + ((size_t)b * C_ + c) * HW;
        out[((size_t)b * C_ + c) * HW + px] =
            advect_one(img, u[i], v[i], dt, sp, cp, lon_p,
                       min_lat, min_lon, inv_dlat, inv_dlon);
    }
}

extern "C" void kernel_launch(void* const* d_in, const int* in_sizes, int n_in,
                              void* d_out, int out_size, void* d_ws, size_t ws_size,
                              hipStream_t stream) {
    const float* hidden   = (const float*)d_in[0];
    const float* lat_grid = (const float*)d_in[1];
    const float* lon_grid = (const float*)d_in[2];
    const float* W_vel    = (const float*)d_in[3];
    const float* b_vel    = (const float*)d_in[4];
    const float* dt_p     = (const float*)d_in[5];
    float* out = (float*)d_out;

    const size_t uv_bytes = (size_t)B_ * O_ * HW * sizeof(float); // 66.4 MB
    if (ws_size >= uv_bytes) {
        float* uv = (float*)d_ws;
        nsl_vel<<<B_ * P1_OG * P1_TILES, P1_PXT, 0, stream>>>(hidden, W_vel, b_vel, uv);
        const int n2 = B_ * C_ * HW;                 // 8,294,400 = 32400*256
        nsl_advect<<<n2 / 256, 256, 0, stream>>>(hidden, lat_grid, lon_grid,
                                                 uv, dt_p, out);
    } else {
        nsl_fused<<<B_ * FB_CG * FB_TILES, FB_PXT, 0, stream>>>(
            hidden, lat_grid, lon_grid, W_vel, b_vel, dt_p, out);
    }
}

// Round 10
// 243.680 us; speedup vs baseline: 1.0347x; 1.0347x over previous
//
#include <hip/hip_runtime.h>
#include <math.h>

// Problem constants (fixed by setup_inputs in the reference)
constexpr int B_ = 2, C_ = 64, H_ = 180, W_ = 360;
constexpr int HW = H_ * W_;             // 64800
constexpr int Hp = H_ + 2, Wp = W_ + 2; // padded dims 182 x 362
constexpr int O_ = 2 * C_;              // 128 velocity outputs

// NOTE (round-5 lesson): the reference's seam mapping is DISCONTINUOUS in lon
// (remainder wraps + clamped 1-px-pad bicubic). Coordinate math must stay
// bit-close to fp32 libm: asinf/atan2f/exact-division remainder only.
__device__ __forceinline__ float frem(float x, float y) {
    return x - floorf(x / y) * y;            // IEEE division, matches jnp
}
// remainder(x, 2): x*0.5f is EXACT (pow2), floor identical to floor(x/2).
__device__ __forceinline__ float frem2(float x) {
    return x - floorf(x * 0.5f) * 2.0f;
}

// bicubic weights, A = -0.75
__device__ __forceinline__ float cub1(float x) {   // |t| <= 1
    return (1.25f * x - 2.25f) * x * x + 1.0f;
}
__device__ __forceinline__ float cub2(float x) {   // 1 < |t| < 2
    return ((-0.75f * x + 3.75f) * x - 6.0f) * x + 3.0f;
}

// Read geo_cyclic_pad(hidden,1)[y][x] directly from the unpadded image.
__device__ __forceinline__ float fetch_pad(const float* __restrict__ img, int y, int x) {
    int wc = x - 1;
    if (x == 0)      wc = W_ - 1;
    if (x == Wp - 1) wc = 0;
    int hh = y - 1;
    bool top = (y == 0), bot = (y == Hp - 1);
    if (top) hh = 0;
    if (bot) hh = H_ - 1;
    if (top || bot) { wc += W_ / 2; if (wc >= W_) wc -= W_; }
    return img[hh * W_ + wc];
}

// Shared phase-2 math: departure point + bicubic sample for one (b,c,px).
__device__ __forceinline__ float advect_one(
    const float* __restrict__ img,   // channel slice (H,W)
    float u, float v, float dt,
    float sp, float cp, float lon_p,
    float min_lat, float min_lon, float inv_dlat, float inv_dlon)
{
    const float two_pi = 6.28318530717958647f;
    const float sxw = (float)W_ / (float)Wp;
    const float syh = (float)H_ / (float)Hp;

    const float lon_pr = -u * dt;
    const float lat_pr = -v * dt;
    float slp, clp, slo, clo;
    __sincosf(lat_pr, &slp, &clp);
    __sincosf(lon_pr, &slo, &clo);
    float sin_lat = slp * cp + clp * clo * sp;
    sin_lat = fminf(fmaxf(sin_lat, -1.0f + 1e-7f), 1.0f - 1e-7f);
    const float lat = asinf(sin_lat);
    const float num = clp * slo;
    const float den = clp * clo * cp - slp * sp;
    const float lon = frem(lon_p + atan2f(num, den) + two_pi, two_pi);

    float gx = (lon - min_lon) * inv_dlon - 1.0f;
    float gy = (lat - min_lat) * inv_dlat - 1.0f;
    gx = frem2(gx + 1.0f) - 1.0f;
    const bool left  = (gx <= 0.0f);
    const bool outer = (fabsf(gy) > 1.0f);
    if (outer) gx += left ? 1.0f : -1.0f;
    if (gy < -1.0f)     gy = -(2.0f + gy);
    else if (gy > 1.0f) gy = 2.0f - gy;
    gx *= sxw;
    gy *= syh;

    const float ix = (gx + 1.0f) * 0.5f * (float)(Wp - 1);
    const float iy = (gy + 1.0f) * 0.5f * (float)(Hp - 1);
    const float fx0 = floorf(ix), fy0 = floorf(iy);
    const float tx = ix - fx0, ty = iy - fy0;
    const int jx = (int)fx0, jy = (int)fy0;

    float t[16];
    const bool interior = (jx >= 2) & (jx <= Wp - 4) & (jy >= 2) & (jy <= Hp - 4);
    if (__all(interior)) {
        const float* __restrict__ p = img + (jy - 2) * W_ + (jx - 2);
#pragma unroll
        for (int r = 0; r < 4; ++r)
#pragma unroll
            for (int cc = 0; cc < 4; ++cc)
                t[r * 4 + cc] = p[r * W_ + cc];
    } else {
        int xs[4], ys[4];
#pragma unroll
        for (int r = 0; r < 4; ++r) {
            xs[r] = min(max(jx - 1 + r, 0), Wp - 1);
            ys[r] = min(max(jy - 1 + r, 0), Hp - 1);
        }
#pragma unroll
        for (int r = 0; r < 4; ++r)
#pragma unroll
            for (int cc = 0; cc < 4; ++cc)
                t[r * 4 + cc] = fetch_pad(img, ys[r], xs[cc]);
    }

    const float wx0 = cub2(tx + 1.0f), wx1 = cub1(tx);
    const float wx2 = cub1(1.0f - tx), wx3 = cub2(2.0f - tx);
    const float wy0 = cub2(ty + 1.0f), wy1 = cub1(ty);
    const float wy2 = cub1(1.0f - ty), wy3 = cub2(2.0f - ty);

    const float r0 = fmaf(wx3, t[3],  fmaf(wx2, t[2],  fmaf(wx1, t[1],  wx0 * t[0])));
    const float r1 = fmaf(wx3, t[7],  fmaf(wx2, t[6],  fmaf(wx1, t[5],  wx0 * t[4])));
    const float r2 = fmaf(wx3, t[11], fmaf(wx2, t[10], fmaf(wx1, t[9],  wx0 * t[8])));
    const float r3 = fmaf(wx3, t[15], fmaf(wx2, t[14], fmaf(wx1, t[13], wx0 * t[12])));

    return fmaf(wy3, r3, fmaf(wy2, r2, fmaf(wy1, r1, wy0 * r0)));
}

// ---------------- Phase 1: uv = hidden x W_vel^T + b  (B,128,HW) ----------------
// r7/r8/r9 all pinned at ~120 us: the invariant was 1.07e9 W lane-loads
// (=16.8M wave-VMEM instrs ~= 112 us of L1/TA issue). Fix: register tiling.
// Thread owns 8 j x 8 px -> every W float4 reused 8x from VGPRs:
// W instrs/thread 4096 -> 128, x instrs 64 -> 128 dwordx4 (L1-served,
// block x-working-set 32 KB). FMA chains stay k-ascending -> bitwise uv.
constexpr int V_JPT  = 8;                     // j per thread
constexpr int V_PPT  = 8;                     // px per thread (float4 x2)
constexpr int V_TILE = 16 * V_PPT;            // 128 px per block (16 pt-groups)
constexpr int V_TILES = (HW + V_TILE - 1) / V_TILE; // 507 (tail block: 32 px)

__global__ __launch_bounds__(256, 3) void nsl_vel(
    const float* __restrict__ hidden, const float* __restrict__ W_vel,
    const float* __restrict__ b_vel, float* __restrict__ uv)
{
    const int bid  = blockIdx.x;
    const int tile = bid % V_TILES;
    const int b    = bid / V_TILES;
    const int tid  = threadIdx.x;
    const int jt   = tid >> 4;                // 0..15
    const int pt   = tid & 15;                // 0..15
    const int j0   = jt * V_JPT;              // 0..120
    const int px   = tile * V_TILE + pt * V_PPT;
    if (px >= HW) return;                     // tail block; no barrier in kernel

    float acc[V_JPT][V_PPT];
#pragma unroll
    for (int jj = 0; jj < V_JPT; ++jj) {
        const float bj = b_vel[j0 + jj];
#pragma unroll
        for (int p = 0; p < V_PPT; ++p) acc[jj][p] = bj;
    }

    const float* hb = hidden + (size_t)b * C_ * HW + px;

#pragma unroll 1                               // keep body I$-resident (~1.3 KB)
    for (int k = 0; k < C_; k += 4) {
        float xv[4][8];
#pragma unroll
        for (int kk = 0; kk < 4; ++kk) {
            *(float4*)&xv[kk][0] = *(const float4*)(hb + (size_t)(k + kk) * HW);
            *(float4*)&xv[kk][4] = *(const float4*)(hb + (size_t)(k + kk) * HW + 4);
        }
        float wv[V_JPT][4];
#pragma unroll
        for (int jj = 0; jj < V_JPT; ++jj)
            *(float4*)&wv[jj][0] = *(const float4*)(W_vel + (size_t)(j0 + jj) * C_ + k);
        // k ascending per (jj,p) chain -> bitwise-identical uv vs rounds 3-8.
#pragma unroll
        for (int jj = 0; jj < V_JPT; ++jj)
#pragma unroll
            for (int kk = 0; kk < 4; ++kk)
#pragma unroll
                for (int p = 0; p < V_PPT; ++p)
                    acc[jj][p] = fmaf(wv[jj][kk], xv[kk][p], acc[jj][p]);
    }

    float* o = uv + ((size_t)b * O_ + j0) * HW + px;
#pragma unroll
    for (int jj = 0; jj < V_JPT; ++jj) {
        *(float4*)(o + (size_t)jj * HW)     = *(float4*)&acc[jj][0];
        *(float4*)(o + (size_t)jj * HW + 4) = *(float4*)&acc[jj][4];
    }
}

// ---------------- Phase 2: one thread per (b,c,px) — round-8 form ----------------
// (r9 LDS sincos table REGRESSED 120->132 us: 32400 per-block barriers +
//  magic-div + LDS round-trip cost more than the saved sincosf. Reverted.)
__global__ __launch_bounds__(256, 6) void nsl_advect(
    const float* __restrict__ hidden,    // (B,C,H,W)
    const float* __restrict__ lat_grid,  // (B,H,W)
    const float* __restrict__ lon_grid,  // (B,H,W)
    const float* __restrict__ uv,        // (B,128,HW) from phase 1
    const float* __restrict__ dt_p,
    float* __restrict__ out)             // (B,C,H,W)
{
    const int idx = blockIdx.x * 256 + threadIdx.x;
    if (idx >= B_ * C_ * HW) return;
    const int px = idx % HW;
    const int bc = idx / HW;            // b*C + c
    const int b  = bc / C_;
    const int c  = bc - b * C_;

    const float dt      = dt_p[0];
    const float min_lat = lat_grid[0];
    const float max_lat = lat_grid[(H_ - 1) * W_];
    const float min_lon = lon_grid[0];
    const float max_lon = lon_grid[W_ - 1];
    const float inv_dlat = 2.0f / (max_lat - min_lat);
    const float inv_dlon = 2.0f / (max_lon - min_lon);

    const float lat_p = lat_grid[(size_t)b * HW + px];
    const float lon_p = lon_grid[(size_t)b * HW + px];
    float sp, cp;
    __sincosf(lat_p, &sp, &cp);

    const float u = uv[((size_t)b * O_ + c) * HW + px];
    const float v = uv[((size_t)b * O_ + C_ + c) * HW + px];

    const float* __restrict__ img = hidden + (size_t)bc * HW;
    out[(size_t)bc * HW + px] = advect_one(img, u, v, dt, sp, cp, lon_p,
                                           min_lat, min_lon, inv_dlat, inv_dlon);
}

// ---------------- Fallback: fused kernel (round-6 structure, passing) ----------------
constexpr int FB_CG = 4, FB_CPT = C_ / FB_CG, FB_PXT = 256;
constexpr int FB_TILES = (HW + FB_PXT - 1) / FB_PXT;

__global__ __launch_bounds__(FB_PXT, 6) void nsl_fused(
    const float* __restrict__ hidden, const float* __restrict__ lat_grid,
    const float* __restrict__ lon_grid, const float* __restrict__ W_vel,
    const float* __restrict__ b_vel, const float* __restrict__ dt_p,
    float* __restrict__ out)
{
    const int bid  = blockIdx.x;
    const int tile = bid % FB_TILES;
    const int cg   = (bid / FB_TILES) % FB_CG;
    const int b    = bid / (FB_TILES * FB_CG);
    const int px   = tile * FB_PXT + threadIdx.x;
    if (px >= HW) return;

    const float dt      = dt_p[0];
    const float min_lat = lat_grid[0];
    const float max_lat = lat_grid[(H_ - 1) * W_];
    const float min_lon = lon_grid[0];
    const float max_lon = lon_grid[W_ - 1];
    const float inv_dlat = 2.0f / (max_lat - min_lat);
    const float inv_dlon = 2.0f / (max_lon - min_lon);

    const float lat_p = lat_grid[(size_t)b * HW + px];
    const float lon_p = lon_grid[(size_t)b * HW + px];
    float sp, cp;
    __sincosf(lat_p, &sp, &cp);

    float u[FB_CPT], v[FB_CPT];
#pragma unroll
    for (int i = 0; i < FB_CPT; ++i) {
        u[i] = b_vel[cg * FB_CPT + i];
        v[i] = b_vel[C_ + cg * FB_CPT + i];
    }
    const float* hb = hidden + (size_t)b * C_ * HW + px;
#pragma unroll 2
    for (int k = 0; k < C_; ++k) {
        const float x = hb[(size_t)k * HW];
#pragma unroll
        for (int i = 0; i < FB_CPT; ++i) {
            u[i] = fmaf(W_vel[(size_t)(cg * FB_CPT + i) * C_ + k], x, u[i]);
            v[i] = fmaf(W_vel[(size_t)(C_ + cg * FB_CPT + i) * C_ + k], x, v[i]);
        }
    }

    for (int i = 0; i < FB_CPT; ++i) {
        const int c = cg * FB_CPT + i;
        const float* __restrict__ img = hidden + ((size_t)b * C_ + c) * HW;
        out[((size_t)b * C_ + c) * HW + px] =
            advect_one(img, u[i], v[i], dt, sp, cp, lon_p,
                       min_lat, min_lon, inv_dlat, inv_dlon);
    }
}

extern "C" void kernel_launch(void* const* d_in, const int* in_sizes, int n_in,
                              void* d_out, int out_size, void* d_ws, size_t ws_size,
                              hipStream_t stream) {
    const float* hidden   = (const float*)d_in[0];
    const float* lat_grid = (const float*)d_in[1];
    const float* lon_grid = (const float*)d_in[2];
    const float* W_vel    = (const float*)d_in[3];
    const float* b_vel    = (const float*)d_in[4];
    const float* dt_p     = (const float*)d_in[5];
    float* out = (float*)d_out;

    const size_t uv_bytes = (size_t)B_ * O_ * HW * sizeof(float); // 66.4 MB
    if (ws_size >= uv_bytes) {
        float* uv = (float*)d_ws;
        nsl_vel<<<B_ * V_TILES, 256, 0, stream>>>(hidden, W_vel, b_vel, uv);
        const int n2 = B_ * C_ * HW;
        nsl_advect<<<(n2 + 255) / 256, 256, 0, stream>>>(hidden, lat_grid, lon_grid,
                                                         uv, dt_p, out);
    } else {
        nsl_fused<<<B_ * FB_CG * FB_TILES, FB_PXT, 0, stream>>>(
            hidden, lat_grid, lon_grid, W_vel, b_vel, dt_p, out);
    }
}

// Round 11
// 239.147 us; speedup vs baseline: 1.0543x; 1.0190x over previous
//
#include <hip/hip_runtime.h>
#include <math.h>

// Problem constants (fixed by setup_inputs in the reference)
constexpr int B_ = 2, C_ = 64, H_ = 180, W_ = 360;
constexpr int HW = H_ * W_;             // 64800
constexpr int Hp = H_ + 2, Wp = W_ + 2; // padded dims 182 x 362
constexpr int O_ = 2 * C_;              // 128 velocity outputs

// 4-byte-aligned float4: the bicubic taps are 4 contiguous floats at arbitrary
// dword alignment; CDNA global_load_dwordx4 only needs dword alignment.
typedef float float4a __attribute__((ext_vector_type(4), aligned(4)));

// NOTE (round-5 lesson): the reference's seam mapping is DISCONTINUOUS in lon
// (remainder wraps + clamped 1-px-pad bicubic). Coordinate math must stay
// bit-close to fp32 libm: asinf/atan2f/exact-division remainder only.
__device__ __forceinline__ float frem(float x, float y) {
    return x - floorf(x / y) * y;            // IEEE division, matches jnp
}
// remainder(x, 2): x*0.5f is EXACT (pow2), floor identical to floor(x/2).
__device__ __forceinline__ float frem2(float x) {
    return x - floorf(x * 0.5f) * 2.0f;
}

// bicubic weights, A = -0.75
__device__ __forceinline__ float cub1(float x) {   // |t| <= 1
    return (1.25f * x - 2.25f) * x * x + 1.0f;
}
__device__ __forceinline__ float cub2(float x) {   // 1 < |t| < 2
    return ((-0.75f * x + 3.75f) * x - 6.0f) * x + 3.0f;
}

// Read geo_cyclic_pad(hidden,1)[y][x] directly from the unpadded image.
__device__ __forceinline__ float fetch_pad(const float* __restrict__ img, int y, int x) {
    int wc = x - 1;
    if (x == 0)      wc = W_ - 1;
    if (x == Wp - 1) wc = 0;
    int hh = y - 1;
    bool top = (y == 0), bot = (y == Hp - 1);
    if (top) hh = 0;
    if (bot) hh = H_ - 1;
    if (top || bot) { wc += W_ / 2; if (wc >= W_) wc -= W_; }
    return img[hh * W_ + wc];
}

// Shared phase-2 math: departure point + bicubic sample for one (b,c,px).
__device__ __forceinline__ float advect_one(
    const float* __restrict__ img,   // channel slice (H,W)
    float u, float v, float dt,
    float sp, float cp, float lon_p,
    float min_lat, float min_lon, float inv_dlat, float inv_dlon)
{
    const float two_pi = 6.28318530717958647f;
    const float sxw = (float)W_ / (float)Wp;
    const float syh = (float)H_ / (float)Hp;

    const float lon_pr = -u * dt;
    const float lat_pr = -v * dt;
    float slp, clp, slo, clo;
    __sincosf(lat_pr, &slp, &clp);
    __sincosf(lon_pr, &slo, &clo);
    float sin_lat = slp * cp + clp * clo * sp;
    sin_lat = fminf(fmaxf(sin_lat, -1.0f + 1e-7f), 1.0f - 1e-7f);
    const float lat = asinf(sin_lat);
    const float num = clp * slo;
    const float den = clp * clo * cp - slp * sp;
    const float lon = frem(lon_p + atan2f(num, den) + two_pi, two_pi);

    float gx = (lon - min_lon) * inv_dlon - 1.0f;
    float gy = (lat - min_lat) * inv_dlat - 1.0f;
    gx = frem2(gx + 1.0f) - 1.0f;
    const bool left  = (gx <= 0.0f);
    const bool outer = (fabsf(gy) > 1.0f);
    if (outer) gx += left ? 1.0f : -1.0f;
    if (gy < -1.0f)     gy = -(2.0f + gy);
    else if (gy > 1.0f) gy = 2.0f - gy;
    gx *= sxw;
    gy *= syh;

    const float ix = (gx + 1.0f) * 0.5f * (float)(Wp - 1);
    const float iy = (gy + 1.0f) * 0.5f * (float)(Hp - 1);
    const float fx0 = floorf(ix), fy0 = floorf(iy);
    const float tx = ix - fx0, ty = iy - fy0;
    const int jx = (int)fx0, jy = (int)fy0;

    float t[16];
    const bool interior = (jx >= 2) & (jx <= Wp - 4) & (jy >= 2) & (jy <= Hp - 4);
    if (__all(interior)) {
        // 4 contiguous floats per row -> one dwordx4 per row (same addresses,
        // bitwise-identical values; just 4 VMEM instrs instead of 16).
        const float* __restrict__ p = img + (jy - 2) * W_ + (jx - 2);
#pragma unroll
        for (int r = 0; r < 4; ++r) {
            const float4a row = *(const float4a*)(p + r * W_);
            t[r * 4 + 0] = row.x;
            t[r * 4 + 1] = row.y;
            t[r * 4 + 2] = row.z;
            t[r * 4 + 3] = row.w;
        }
    } else {
        int xs[4], ys[4];
#pragma unroll
        for (int r = 0; r < 4; ++r) {
            xs[r] = min(max(jx - 1 + r, 0), Wp - 1);
            ys[r] = min(max(jy - 1 + r, 0), Hp - 1);
        }
#pragma unroll
        for (int r = 0; r < 4; ++r)
#pragma unroll
            for (int cc = 0; cc < 4; ++cc)
                t[r * 4 + cc] = fetch_pad(img, ys[r], xs[cc]);
    }

    const float wx0 = cub2(tx + 1.0f), wx1 = cub1(tx);
    const float wx2 = cub1(1.0f - tx), wx3 = cub2(2.0f - tx);
    const float wy0 = cub2(ty + 1.0f), wy1 = cub1(ty);
    const float wy2 = cub1(1.0f - ty), wy3 = cub2(2.0f - ty);

    const float r0 = fmaf(wx3, t[3],  fmaf(wx2, t[2],  fmaf(wx1, t[1],  wx0 * t[0])));
    const float r1 = fmaf(wx3, t[7],  fmaf(wx2, t[6],  fmaf(wx1, t[5],  wx0 * t[4])));
    const float r2 = fmaf(wx3, t[11], fmaf(wx2, t[10], fmaf(wx1, t[9],  wx0 * t[8])));
    const float r3 = fmaf(wx3, t[15], fmaf(wx2, t[14], fmaf(wx1, t[13], wx0 * t[12])));

    return fmaf(wy3, r3, fmaf(wy2, r2, fmaf(wy1, r1, wy0 * r0)));
}

// ---------------- Phase 1: uv = hidden x W_vel^T + b  (B,128,HW) ----------------
// r7-r10: four structurally different GEMMs (OPG32/OPG64/rolled/8x8 regtile)
// all land at the same time -> vel is bound by its 100 MB HBM round-trip
// (hidden read + uv write), not by its instruction stream. Keep the simplest
// variant that produced the best measured total (r8).
constexpr int P1_PXT = 256;
constexpr int P1_OG  = 2;
constexpr int P1_OPG = O_ / P1_OG;      // 64 outputs per group
constexpr int P1_TILES = (HW + P1_PXT - 1) / P1_PXT; // 254

__global__ __launch_bounds__(P1_PXT, 4) void nsl_vel(
    const float* __restrict__ hidden, const float* __restrict__ W_vel,
    const float* __restrict__ b_vel, float* __restrict__ uv)
{
    const int bid  = blockIdx.x;
    const int tile = bid % P1_TILES;
    const int og   = (bid / P1_TILES) % P1_OG;
    const int b    = bid / (P1_TILES * P1_OG);
    const int px   = tile * P1_PXT + threadIdx.x;
    if (px >= HW) return;

    float acc[P1_OPG];
#pragma unroll
    for (int j = 0; j < P1_OPG; ++j) acc[j] = b_vel[og * P1_OPG + j];

    const float* hb = hidden + (size_t)b * C_ * HW + px;
    const float* Wg = W_vel + (size_t)og * P1_OPG * C_;

    float xf[4];
#pragma unroll
    for (int t = 0; t < 4; ++t) xf[t] = hb[(size_t)t * HW];

    for (int k0 = 0; k0 < C_; k0 += 4) {
        float xc[4];
#pragma unroll
        for (int t = 0; t < 4; ++t) xc[t] = xf[t];
        if (k0 + 4 < C_) {
#pragma unroll
            for (int t = 0; t < 4; ++t) xf[t] = hb[(size_t)(k0 + 4 + t) * HW];
        }
        // k-chain per output stays ascending -> bitwise-identical uv.
#pragma unroll
        for (int j = 0; j < P1_OPG; ++j) {
            const float* wr = Wg + (size_t)j * C_ + k0;
            acc[j] = fmaf(wr[0], xc[0], acc[j]);
            acc[j] = fmaf(wr[1], xc[1], acc[j]);
            acc[j] = fmaf(wr[2], xc[2], acc[j]);
            acc[j] = fmaf(wr[3], xc[3], acc[j]);
        }
    }

    float* o = uv + ((size_t)b * O_ + og * P1_OPG) * HW + px;
#pragma unroll
    for (int j = 0; j < P1_OPG; ++j) o[(size_t)j * HW] = acc[j];
}

// ---------------- Phase 2: 2D grid (px-tile, bc) ----------------
// blockIdx.y = b*C + c (block-uniform channel -> scalar uv/img bases);
// no 64-bit idx decode per thread.
constexpr int P2_TILES = (HW + 255) / 256;   // 254

__global__ __launch_bounds__(256, 8) void nsl_advect(
    const float* __restrict__ hidden,    // (B,C,H,W)
    const float* __restrict__ lat_grid,  // (B,H,W)
    const float* __restrict__ lon_grid,  // (B,H,W)
    const float* __restrict__ uv,        // (B,128,HW) from phase 1
    const float* __restrict__ dt_p,
    float* __restrict__ out)             // (B,C,H,W)
{
    const int px = blockIdx.x * 256 + threadIdx.x;
    if (px >= HW) return;
    const int bc = blockIdx.y;          // b*C + c
    const int b  = bc >> 6;             // / C_
    const int c  = bc & (C_ - 1);

    const float dt      = dt_p[0];
    const float min_lat = lat_grid[0];
    const float max_lat = lat_grid[(H_ - 1) * W_];
    const float min_lon = lon_grid[0];
    const float max_lon = lon_grid[W_ - 1];
    const float inv_dlat = 2.0f / (max_lat - min_lat);
    const float inv_dlon = 2.0f / (max_lon - min_lon);

    const float lat_p = lat_grid[(size_t)b * HW + px];
    const float lon_p = lon_grid[(size_t)b * HW + px];
    float sp, cp;
    __sincosf(lat_p, &sp, &cp);

    const float u = uv[((size_t)b * O_ + c) * HW + px];
    const float v = uv[((size_t)b * O_ + C_ + c) * HW + px];

    const float* __restrict__ img = hidden + (size_t)bc * HW;
    out[(size_t)bc * HW + px] = advect_one(img, u, v, dt, sp, cp, lon_p,
                                           min_lat, min_lon, inv_dlat, inv_dlon);
}

// ---------------- Fallback: fused kernel (round-6 structure, passing) ----------------
constexpr int FB_CG = 4, FB_CPT = C_ / FB_CG, FB_PXT = 256;
constexpr int FB_TILES = (HW + FB_PXT - 1) / FB_PXT;

__global__ __launch_bounds__(FB_PXT, 6) void nsl_fused(
    const float* __restrict__ hidden, const float* __restrict__ lat_grid,
    const float* __restrict__ lon_grid, const float* __restrict__ W_vel,
    const float* __restrict__ b_vel, const float* __restrict__ dt_p,
    float* __restrict__ out)
{
    const int bid  = blockIdx.x;
    const int tile = bid % FB_TILES;
    const int cg   = (bid / FB_TILES) % FB_CG;
    const int b    = bid / (FB_TILES * FB_CG);
    const int px   = tile * FB_PXT + threadIdx.x;
    if (px >= HW) return;

    const float dt      = dt_p[0];
    const float min_lat = lat_grid[0];
    const float max_lat = lat_grid[(H_ - 1) * W_];
    const float min_lon = lon_grid[0];
    const float max_lon = lon_grid[W_ - 1];
    const float inv_dlat = 2.0f / (max_lat - min_lat);
    const float inv_dlon = 2.0f / (max_lon - min_lon);

    const float lat_p = lat_grid[(size_t)b * HW + px];
    const float lon_p = lon_grid[(size_t)b * HW + px];
    float sp, cp;
    __sincosf(lat_p, &sp, &cp);

    float u[FB_CPT], v[FB_CPT];
#pragma unroll
    for (int i = 0; i < FB_CPT; ++i) {
        u[i] = b_vel[cg * FB_CPT + i];
        v[i] = b_vel[C_ + cg * FB_CPT + i];
    }
    const float* hb = hidden + (size_t)b * C_ * HW + px;
#pragma unroll 2
    for (int k = 0; k < C_; ++k) {
        const float x = hb[(size_t)k * HW];
#pragma unroll
        for (int i = 0; i < FB_CPT; ++i) {
            u[i] = fmaf(W_vel[(size_t)(cg * FB_CPT + i) * C_ + k], x, u[i]);
            v[i] = fmaf(W_vel[(size_t)(C_ + cg * FB_CPT + i) * C_ + k], x, v[i]);
        }
    }

    for (int i = 0; i < FB_CPT; ++i) {
        const int c = cg * FB_CPT + i;
        const float* __restrict__ img = hidden + ((size_t)b * C_ + c) * HW;
        out[((size_t)b * C_ + c) * HW + px] =
            advect_one(img, u[i], v[i], dt, sp, cp, lon_p,
                       min_lat, min_lon, inv_dlat, inv_dlon);
    }
}

extern "C" void kernel_launch(void* const* d_in, const int* in_sizes, int n_in,
                              void* d_out, int out_size, void* d_ws, size_t ws_size,
                              hipStream_t stream) {
    const float* hidden   = (const float*)d_in[0];
    const float* lat_grid = (const float*)d_in[1];
    const float* lon_grid = (const float*)d_in[2];
    const float* W_vel    = (const float*)d_in[3];
    const float* b_vel    = (const float*)d_in[4];
    const float* dt_p     = (const float*)d_in[5];
    float* out = (float*)d_out;

    const size_t uv_bytes = (size_t)B_ * O_ * HW * sizeof(float); // 66.4 MB
    if (ws_size >= uv_bytes) {
        float* uv = (float*)d_ws;
        nsl_vel<<<B_ * P1_OG * P1_TILES, P1_PXT, 0, stream>>>(hidden, W_vel, b_vel, uv);
        nsl_advect<<<dim3(P2_TILES, B_ * C_), 256, 0, stream>>>(
            hidden, lat_grid, lon_grid, uv, dt_p, out);
    } else {
        nsl_fused<<<B_ * FB_CG * FB_TILES, FB_PXT, 0, stream>>>(
            hidden, lat_grid, lon_grid, W_vel, b_vel, dt_p, out);
    }
}